// Round 2
// baseline (264.110 us; speedup 1.0000x reference)
//
#include <hip/hip_runtime.h>
#include <hip/hip_bf16.h>
#include <cstdint>

// B=8, N=1024, D=1024, H=16, hd=64, scale=1/8.
// Facts: inputs fp32, output fp32, ws = 64 MiB, threshold 1.47e-3 (bf16
// intermediates give 4.9e-4 — R6/R7 verified). R7 swizzled-LDS GEMM verified
// on HW (0 bank conflicts, correct). R8: A pre-converted to bf16 (d_out as
// scratch), softmax without max-subtraction (shift-invariant; scores |s|<~3).
// R9: attention on 32x32x16 MFMA, swapped QK^T, in-register P redistribution
// (cvt_pk_bf16 + permlane32_swap), no Ps LDS. Verified (absmax 4.9e-4).
// R10: QKV GEMM ported to the 8-phase 256x256 schedule (T3+T4+T5): counted
// vmcnt(4) at phases 4/8 only (never 0 mid-loop), raw s_barrier +
// lgkmcnt(0) + sched_barrier(0), setprio around MFMA clusters, 128 KiB
// double-buffered LDS (dynamic + hipFuncSetAttribute). Quadrant order
// (0,0)(0,1)(1,1)(1,0); stagger: ph1 A1(t+1), ph2 B0(t+1), ph3 A0(t+2),
// ph4 B1(t+2)+vmcnt4, ph5 A1(t+2), ph6 B0(t+2), ph7 A0(t+3),
// ph8 B1(t+3)+vmcnt4. Overwrite-safety and landing guarantees derived and
// checked per half-tile. Proj GEMM stays on the R7 kernel (risk isolation).

typedef __attribute__((ext_vector_type(8))) short short8;   // 8 bf16
typedef __attribute__((ext_vector_type(4))) float floatx4;  // 16x16 MFMA acc
typedef __attribute__((ext_vector_type(16))) float f32x16;  // 32x32 MFMA acc
typedef __attribute__((ext_vector_type(2))) unsigned int uint2v;

__device__ __forceinline__ ushort f2bf(float f) {
    union { float f; uint32_t i; } v; v.f = f;
    uint32_t r = v.i + 0x7fffu + ((v.i >> 16) & 1u);  // RNE
    return (ushort)(r >> 16);
}
__device__ __forceinline__ uint32_t pack2(float a, float b) {
    return (uint32_t)f2bf(a) | ((uint32_t)f2bf(b) << 16);
}
__device__ __forceinline__ uint32_t cvtpk_bf16(float a, float b) {
    uint32_t r;
    asm("v_cvt_pk_bf16_f32 %0, %1, %2" : "=v"(r) : "v"(a), "v"(b));
    return r;  // low16 = bf16(a), high16 = bf16(b)
}
__device__ __forceinline__ void gl2lds16(const void* g, void* lds) {
    __builtin_amdgcn_global_load_lds(
        (const __attribute__((address_space(1))) uint32_t*)(uintptr_t)g,
        (__attribute__((address_space(3))) uint32_t*)(uintptr_t)lds,
        16, 0, 0);
}

// ---------------------------------------------------------------------------
// A prep: fp32 -> bf16, contiguous. 8 floats/thread.
// ---------------------------------------------------------------------------
__global__ __launch_bounds__(256)
void aprep(const float* __restrict__ in, ushort* __restrict__ ob) {
    const int i = (blockIdx.x * 256 + threadIdx.x) * 8;
    const float4 f0 = *(const float4*)&in[i];
    const float4 f1 = *(const float4*)&in[i + 4];
    uint4 pk;
    pk.x = pack2(f0.x, f0.y); pk.y = pack2(f0.z, f0.w);
    pk.z = pack2(f1.x, f1.y); pk.w = pack2(f1.z, f1.w);
    *(uint4*)&ob[i] = pk;
}

// ---------------------------------------------------------------------------
// Weight prep: W fp32 [K,N] -> WT bf16 [N,K].
// ---------------------------------------------------------------------------
__global__ __launch_bounds__(256)
void wprep(const float* __restrict__ W, ushort* __restrict__ WT,
           int K, int N) {
    __shared__ ushort T[64 * 72];
    const int tid = threadIdx.x;
    const int k0 = blockIdx.y * 64, n0 = blockIdx.x * 64;
#pragma unroll
    for (int i = 0; i < 4; ++i) {
        int c = tid + i * 256;
        int kl = c >> 4, n4 = (c & 15) << 2;
        const float4 f = *(const float4*)&W[(size_t)(k0 + kl) * N + n0 + n4];
        T[(n4 + 0) * 72 + kl] = f2bf(f.x);
        T[(n4 + 1) * 72 + kl] = f2bf(f.y);
        T[(n4 + 2) * 72 + kl] = f2bf(f.z);
        T[(n4 + 3) * 72 + kl] = f2bf(f.w);
    }
    __syncthreads();
#pragma unroll
    for (int i = 0; i < 2; ++i) {
        int c = tid + i * 256;
        int nl = c >> 3, k8 = (c & 7) << 3;
        *(uint4*)&WT[(size_t)(n0 + nl) * K + k0 + k8] =
            *(const uint4*)&T[nl * 72 + k8];
    }
}

// ---------------------------------------------------------------------------
// R7 BT-GEMM (2-phase, 128x128): kept for the proj GEMM. MODE 0 only now.
// ---------------------------------------------------------------------------
template <int MODE, typename OutT>
__global__ __launch_bounds__(256)
void gemm_bt(const ushort* __restrict__ A, const ushort* __restrict__ BT,
             const float* __restrict__ bias, OutT* __restrict__ C,
             ushort* __restrict__ qb, ushort* __restrict__ kb,
             ushort* __restrict__ vb, int M, int Nn, int K) {
    __shared__ ushort As[128 * 64];
    __shared__ ushort Bs[128 * 64];
    const int tid = threadIdx.x;
    const int lane = tid & 63, w = tid >> 6;
    const int wm = w & 1, wn = w >> 1;
    const int l16 = lane & 15, quad = lane >> 4;
    const int m0 = blockIdx.y * 128, n0 = blockIdx.x * 128;
    const int srow = lane >> 3;
    const int cg = (lane & 7) ^ srow;
    const int sx = l16 & 7;

    floatx4 acc[4][4];
#pragma unroll
    for (int i = 0; i < 4; ++i)
#pragma unroll
        for (int j = 0; j < 4; ++j) acc[i][j] = (floatx4)0.f;

    const int nkt = K >> 6;
    for (int kt = 0; kt < nkt; ++kt) {
        __syncthreads();
#pragma unroll
        for (int i = 0; i < 4; ++i) {
            const int row = w * 32 + i * 8 + srow;
            gl2lds16(&BT[(size_t)(n0 + row) * K + kt * 64 + cg * 8],
                     &Bs[(w * 32 + i * 8) * 64]);
            gl2lds16(&A[(size_t)(m0 + row) * K + kt * 64 + cg * 8],
                     &As[(w * 32 + i * 8) * 64]);
        }
        __syncthreads();
#pragma unroll
        for (int kk = 0; kk < 2; ++kk) {
            const int sl = ((kk << 2) | quad) ^ sx;
            short8 af[4], bfr[4];
#pragma unroll
            for (int mi = 0; mi < 4; ++mi)
                af[mi] = *(const short8*)&As[(wm * 64 + mi * 16 + l16) * 64 +
                                             sl * 8];
#pragma unroll
            for (int ni = 0; ni < 4; ++ni)
                bfr[ni] = *(const short8*)&Bs[(wn * 64 + ni * 16 + l16) * 64 +
                                              sl * 8];
#pragma unroll
            for (int mi = 0; mi < 4; ++mi)
#pragma unroll
                for (int ni = 0; ni < 4; ++ni)
                    acc[mi][ni] = __builtin_amdgcn_mfma_f32_16x16x32_bf16(
                        af[mi], bfr[ni], acc[mi][ni], 0, 0, 0);
        }
    }

#pragma unroll
    for (int mi = 0; mi < 4; ++mi) {
#pragma unroll
        for (int ni = 0; ni < 4; ++ni) {
            const int jg = n0 + wn * 64 + ni * 16 + l16;
            const float bv = bias[jg];
#pragma unroll
            for (int r = 0; r < 4; ++r) {
                const int mg = m0 + wm * 64 + mi * 16 + quad * 4 + r;
                const float vout = acc[mi][ni][r] + bv;
                if (MODE == 0) {
                    if (sizeof(OutT) == 4)
                        ((float*)C)[(size_t)mg * Nn + jg] = vout;
                    else
                        ((ushort*)C)[(size_t)mg * Nn + jg] = f2bf(vout);
                } else {
                    const int which = jg >> 10;
                    const int h = (jg & 1023) >> 6;
                    const int d = jg & 63;
                    const int bb = mg >> 10, nn = mg & 1023;
                    if (which == 0)
                        qb[(size_t)((bb * 16 + h) * 1024 + nn) * 64 + d] =
                            f2bf(vout);
                    else if (which == 1)
                        kb[(size_t)((bb * 16 + h) * 1024 + nn) * 64 + d] =
                            f2bf(vout);
                    else
                        vb[((size_t)(bb * 16 + h) * 64 + d) * 1024 + nn] =
                            f2bf(vout);
                }
            }
        }
    }
}

// ---------------------------------------------------------------------------
// 8-phase 256x256 BT-GEMM (T3+T4+T5). 512 threads = 8 waves (2x4 per
// 128x128 quadrant). LDS 128 KiB: [slot][A/B][half][128*64] bf16, R7
// XOR-granule swizzle. One half-tile staged per phase (2 gl2lds/thread);
// vmcnt(4) at phases 4 and 8 only. MODE as gemm_bt.
// ---------------------------------------------------------------------------
#define STAGE8(mat, half, kt) do {                                            \
    const ushort* _src = (mat) ? BT : A;                                      \
    const int _b0 = ((mat) ? n0 : m0) + (half) * 128;                         \
    ushort* _d = &lds[((((kt) & 1) * 2 + (mat)) * 2 + (half)) * 8192];        \
    _Pragma("unroll")                                                         \
    for (int g = 0; g < 2; ++g)                                               \
        gl2lds16(&_src[(size_t)(_b0 + w * 16 + g * 8 + srow) * K +            \
                       (kt) * 64 + cg * 8],                                   \
                 &_d[(w * 16 + g * 8) * 64]);                                 \
} while (0)

#define LDA8(mq, s) do {                                                      \
    _Pragma("unroll")                                                         \
    for (int mi = 0; mi < 4; ++mi)                                            \
        _Pragma("unroll")                                                     \
        for (int kk = 0; kk < 2; ++kk)                                        \
            af[mi][kk] = *(const short8*)&lds[                                \
                (((s) * 2 + 0) * 2 + (mq)) * 8192 +                           \
                (wqm * 64 + mi * 16 + l16) * 64 +                             \
                ((((kk << 2) | quad) ^ sx) << 3)];                            \
} while (0)

#define LDB8(nq, s) do {                                                      \
    _Pragma("unroll")                                                         \
    for (int ni = 0; ni < 2; ++ni)                                            \
        _Pragma("unroll")                                                     \
        for (int kk = 0; kk < 2; ++kk)                                        \
            bf[ni][kk] = *(const short8*)&lds[                                \
                (((s) * 2 + 1) * 2 + (nq)) * 8192 +                           \
                (wqn * 32 + ni * 16 + l16) * 64 +                             \
                ((((kk << 2) | quad) ^ sx) << 3)];                            \
} while (0)

#define MMA8(mq, nq) do {                                                     \
    __builtin_amdgcn_s_setprio(1);                                            \
    _Pragma("unroll")                                                         \
    for (int kk = 0; kk < 2; ++kk)                                            \
        _Pragma("unroll")                                                     \
        for (int mi = 0; mi < 4; ++mi)                                        \
            _Pragma("unroll")                                                 \
            for (int ni = 0; ni < 2; ++ni)                                    \
                acc[mq][nq][mi][ni] =                                         \
                    __builtin_amdgcn_mfma_f32_16x16x32_bf16(                  \
                        af[mi][kk], bf[ni][kk], acc[mq][nq][mi][ni],          \
                        0, 0, 0);                                             \
    __builtin_amdgcn_s_setprio(0);                                            \
} while (0)

#define BAR8() __builtin_amdgcn_s_barrier()
#define WLGKM8() do {                                                         \
    asm volatile("s_waitcnt lgkmcnt(0)" ::: "memory");                        \
    __builtin_amdgcn_sched_barrier(0);                                        \
} while (0)

template <int MODE, typename OutT>
__global__ __launch_bounds__(512, 2)
void gemm8p(const ushort* __restrict__ A, const ushort* __restrict__ BT,
            const float* __restrict__ bias, OutT* __restrict__ C,
            ushort* __restrict__ qb, ushort* __restrict__ kb,
            ushort* __restrict__ vb, int M, int Nn, int K) {
    extern __shared__ ushort lds[];  // [slot][mat][half][128*64] = 128 KiB
    const int tid = threadIdx.x;
    const int lane = tid & 63, w = tid >> 6;       // 8 waves
    const int wqm = w & 1, wqn = w >> 1;           // 2x4 split of a quadrant
    const int l16 = lane & 15, quad = lane >> 4;
    const int srow = lane >> 3;
    const int cg = (lane & 7) ^ srow;
    const int sx = l16 & 7;
    const int m0 = blockIdx.y * 256, n0 = blockIdx.x * 256;

    floatx4 acc[2][2][4][2];
#pragma unroll
    for (int a = 0; a < 2; ++a)
#pragma unroll
        for (int b = 0; b < 2; ++b)
#pragma unroll
            for (int c = 0; c < 4; ++c)
#pragma unroll
                for (int d = 0; d < 2; ++d) acc[a][b][c][d] = (floatx4)0.f;

    short8 af[4][2], bf[2][2];

    const int nkt = K >> 6, niter = nkt >> 1;  // K=1024: 16 tiles, 8 iters

    // Prologue: tile0 all 4 halves + A0(1),B1(1); complete tile0, leave
    // A0(1),B1(1) in flight (steady-state pre-ph1 invariant).
    STAGE8(0, 0, 0); STAGE8(1, 0, 0); STAGE8(0, 1, 0); STAGE8(1, 1, 0);
    STAGE8(0, 0, 1); STAGE8(1, 1, 1);
    asm volatile("s_waitcnt vmcnt(4)" ::: "memory");
    BAR8();

    for (int i = 0; i < niter; ++i) {
        const int t = 2 * i;
        const bool more2 = (t + 2 < nkt), more3 = (t + 3 < nkt);
        // ph1: quadrant (0,0) of tile t (slot0); stage A1(t+1)
        LDA8(0, 0); LDB8(0, 0);
        STAGE8(0, 1, t + 1);
        BAR8(); WLGKM8(); MMA8(0, 0); BAR8();
        // ph2: (0,1); stage B0(t+1)
        LDB8(1, 0);
        STAGE8(1, 0, t + 1);
        BAR8(); WLGKM8(); MMA8(0, 1); BAR8();
        // ph3: (1,1); stage A0(t+2)  [A0(t) dead after ph2]
        LDA8(1, 0);
        if (more2) STAGE8(0, 0, t + 2);
        BAR8(); WLGKM8(); MMA8(1, 1); BAR8();
        // ph4: (1,0); stage B1(t+2) [B1(t) dead after ph3]; vmcnt -> t+1 ready
        LDB8(0, 0);
        if (more2) {
            STAGE8(1, 1, t + 2);
            asm volatile("s_waitcnt vmcnt(4)" ::: "memory");
        } else {
            asm volatile("s_waitcnt vmcnt(0)" ::: "memory");
        }
        BAR8(); WLGKM8(); MMA8(1, 0); BAR8();
        // ph5: (0,0) of tile t+1 (slot1); stage A1(t+2) [A1(t) dead]
        LDA8(0, 1); LDB8(0, 1);
        if (more2) STAGE8(0, 1, t + 2);
        BAR8(); WLGKM8(); MMA8(0, 0); BAR8();
        // ph6: (0,1); stage B0(t+2) [B0(t) dead after ph4]
        LDB8(1, 1);
        if (more2) STAGE8(1, 0, t + 2);
        BAR8(); WLGKM8(); MMA8(0, 1); BAR8();
        // ph7: (1,1); stage A0(t+3) [A0(t+1) dead after ph6]
        LDA8(1, 1);
        if (more3) STAGE8(0, 0, t + 3);
        BAR8(); WLGKM8(); MMA8(1, 1); BAR8();
        // ph8: (1,0); stage B1(t+3) [B1(t+1) dead after ph7]; vmcnt -> t+2
        LDB8(0, 1);
        if (more3) STAGE8(1, 1, t + 3);
        if (more2) asm volatile("s_waitcnt vmcnt(4)" ::: "memory");
        BAR8(); WLGKM8(); MMA8(1, 0); BAR8();
    }

    // Epilogue: acc[mq][nq][mi][ni][r] ->
    //   row = m0 + mq*128 + wqm*64 + mi*16 + quad*4 + r
    //   col = n0 + nq*128 + wqn*32 + ni*16 + l16
#pragma unroll
    for (int mq = 0; mq < 2; ++mq)
#pragma unroll
        for (int nq = 0; nq < 2; ++nq)
#pragma unroll
            for (int ni = 0; ni < 2; ++ni) {
                const int jg = n0 + nq * 128 + wqn * 32 + ni * 16 + l16;
                const float bv = bias[jg];
#pragma unroll
                for (int mi = 0; mi < 4; ++mi)
#pragma unroll
                    for (int r = 0; r < 4; ++r) {
                        const int mg = m0 + mq * 128 + wqm * 64 + mi * 16 +
                                       quad * 4 + r;
                        const float vout = acc[mq][nq][mi][ni][r] + bv;
                        if (MODE == 0) {
                            if (sizeof(OutT) == 4)
                                ((float*)C)[(size_t)mg * Nn + jg] = vout;
                            else
                                ((ushort*)C)[(size_t)mg * Nn + jg] = f2bf(vout);
                        } else {
                            const int which = jg >> 10;
                            const int h = (jg & 1023) >> 6;
                            const int d = jg & 63;
                            const int bb = mg >> 10, nn = mg & 1023;
                            if (which == 0)
                                qb[(size_t)((bb * 16 + h) * 1024 + nn) * 64 +
                                   d] = f2bf(vout);
                            else if (which == 1)
                                kb[(size_t)((bb * 16 + h) * 1024 + nn) * 64 +
                                   d] = f2bf(vout);
                            else  // V pre-transposed: [B,H,hd,N]
                                vb[((size_t)(bb * 16 + h) * 64 + d) * 1024 +
                                   nn] = f2bf(vout);
                        }
                    }
            }
}

// ---------------------------------------------------------------------------
// Flash attention (R9): 32x32x16 MFMA, swapped QK^T, in-register P.
// ---------------------------------------------------------------------------
__global__ __launch_bounds__(256, 4)
void attn_kernel(const ushort* __restrict__ q, const ushort* __restrict__ k,
                 const ushort* __restrict__ v, ushort* __restrict__ o) {
    __shared__ ushort Qs[128 * 64];
    __shared__ ushort Ks[64 * 64];
    __shared__ ushort VTs[64 * 64];      // VT[d][key]
    const int tid = threadIdx.x;
    const int lane = tid & 63, w = tid >> 6;
    const int l31 = lane & 31, hi = lane >> 5, l7 = lane & 7;
    const int h = blockIdx.x, qt = blockIdx.y, b = blockIdx.z;
    const size_t head_off = (size_t)(b * 16 + h) * 1024 * 64;
    const ushort* Qp = q + head_off + (size_t)qt * 128 * 64;
    const ushort* Vp = v + head_off;     // [64 d][1024 key]
    const int srow = lane >> 3;
    const int cg = (lane & 7) ^ srow;
    const float CEXP = 0.125f * 1.44269504f;  // scale * log2(e)

#pragma unroll
    for (int g = 0; g < 4; ++g)
        gl2lds16(&Qp[(size_t)(w * 32 + g * 8 + srow) * 64 + cg * 8],
                 &Qs[(w * 32 + g * 8) * 64]);
    __syncthreads();

    short8 bq[4];
#pragma unroll
    for (int c = 0; c < 4; ++c)
        bq[c] = *(const short8*)&Qs[(w * 32 + l31) * 64 +
                                    ((2 * c + hi) ^ l7) * 8];

    f32x16 oacc[2];
    oacc[0] = (f32x16)0.f;
    oacc[1] = (f32x16)0.f;
    float ls = 0.f;

    for (int kt = 0; kt < 16; ++kt) {
        __syncthreads();
        const ushort* Kp = k + head_off + (size_t)kt * 64 * 64;
#pragma unroll
        for (int g = 0; g < 2; ++g) {
            gl2lds16(&Kp[(size_t)(w * 16 + g * 8 + srow) * 64 + cg * 8],
                     &Ks[(w * 16 + g * 8) * 64]);
            gl2lds16(&Vp[(size_t)(w * 16 + g * 8 + srow) * 1024 +
                         kt * 64 + cg * 8],
                     &VTs[(w * 16 + g * 8) * 64]);
        }
        __syncthreads();

#pragma unroll
        for (int st = 0; st < 2; ++st) {
            f32x16 sacc = (f32x16)0.f;
#pragma unroll
            for (int c = 0; c < 4; ++c) {
                short8 ak = *(const short8*)&Ks[(st * 32 + l31) * 64 +
                                                ((2 * c + hi) ^ l7) * 8];
                sacc = __builtin_amdgcn_mfma_f32_32x32x16_bf16(
                    ak, bq[c], sacc, 0, 0, 0);
            }
            uint32_t wd[8];
#pragma unroll
            for (int i = 0; i < 8; ++i) {
                const float e0 = __builtin_amdgcn_exp2f(sacc[2 * i] * CEXP);
                const float e1 = __builtin_amdgcn_exp2f(sacc[2 * i + 1] * CEXP);
                ls += e0 + e1;
                wd[i] = cvtpk_bf16(e0, e1);
            }
            short8 ap[2];
#pragma unroll
            for (int c2 = 0; c2 < 2; ++c2) {
                uint2v sA = __builtin_amdgcn_permlane32_swap(
                    wd[4 * c2 + 0], wd[4 * c2 + 2], false, false);
                uint2v sB = __builtin_amdgcn_permlane32_swap(
                    wd[4 * c2 + 1], wd[4 * c2 + 3], false, false);
                union { uint32_t u[4]; short8 s; } t;
                t.u[0] = sA[0]; t.u[1] = sB[0];
                t.u[2] = sA[1]; t.u[3] = sB[1];
                ap[c2] = t.s;
            }
#pragma unroll
            for (int dt = 0; dt < 2; ++dt)
#pragma unroll
                for (int c2 = 0; c2 < 2; ++c2) {
                    short8 bv = *(const short8*)&VTs[
                        (dt * 32 + l31) * 64 +
                        ((st * 4 + c2 * 2 + hi) ^ l7) * 8];
                    oacc[dt] = __builtin_amdgcn_mfma_f32_32x32x16_bf16(
                        ap[c2], bv, oacc[dt], 0, 0, 0);
                }
        }
    }

    ls += __shfl_xor(ls, 32, 64);
    const float inv = 1.f / ls;

#pragma unroll
    for (int r = 0; r < 16; ++r) {
        const int qout = (r & 3) + ((r >> 2) << 3) + (hi << 2);
        const float iq = __shfl(inv, qout, 64);
        const int n = qt * 128 + w * 32 + qout;
#pragma unroll
        for (int dt = 0; dt < 2; ++dt)
            o[((size_t)(b * 1024 + n)) * 1024 + h * 64 + dt * 32 + l31] =
                f2bf(oacc[dt][r] * iq);
    }
}

// ---------------------------------------------------------------------------
extern "C" void kernel_launch(void* const* d_in, const int* in_sizes, int n_in,
                              void* d_out, int out_size, void* d_ws,
                              size_t ws_size, hipStream_t stream) {
    const void *inp = d_in[0], *w_qkv = d_in[1], *b_qkv = d_in[2],
               *w_proj = d_in[3], *b_proj = d_in[4];
    for (int i = 0; i < n_in; ++i) {
        switch (in_sizes[i]) {
            case 8 * 1024 * 1024: inp    = d_in[i]; break;
            case 3 * 1024 * 1024: w_qkv  = d_in[i]; break;
            case 3072:            b_qkv  = d_in[i]; break;
            case 1024 * 1024:     w_proj = d_in[i]; break;
            case 1024:            b_proj = d_in[i]; break;
        }
    }
    float* out = (float*)d_out;

    char* ws = (char*)d_ws;
    ushort* qb  = (ushort*)(ws);
    ushort* kb  = (ushort*)(ws + (size_t)16 * 1024 * 1024);
    ushort* vbT = (ushort*)(ws + (size_t)32 * 1024 * 1024);
    ushort* ob  = (ushort*)(ws + (size_t)48 * 1024 * 1024);
    ushort* wqkvT  = ob;
    ushort* wprojT = qb;
    ushort* abf = (ushort*)d_out;   // 16.8 MB bf16 scratch inside d_out

    // allow 128 KiB dynamic LDS for the 8-phase GEMM (immediate host-side
    // config; idempotent; not a stream op -> graph-capture safe)
    hipFuncSetAttribute(reinterpret_cast<const void*>(&gemm8p<1, ushort>),
                        hipFuncAttributeMaxDynamicSharedMemorySize, 131072);

    // t0: inp fp32 -> bf16 (d_out scratch); w_qkv -> wqkvT
    aprep<<<8 * 1024 * 1024 / (256 * 8), 256, 0, stream>>>(
        (const float*)inp, abf);
    wprep<<<dim3(3072 / 64, 1024 / 64), 256, 0, stream>>>(
        (const float*)w_qkv, wqkvT, 1024, 3072);

    // t1: QKV GEMM (8-phase 256x256) -> scatter q/k/vT
    gemm8p<1, ushort><<<dim3(3072 / 256, 8192 / 256), 512, 131072, stream>>>(
        abf, wqkvT, (const float*)b_qkv, (ushort*)nullptr, qb, kb, vbT,
        8192, 3072, 1024);

    // t2: attention — grid (h, qt, b): head-major for XCD/L2 locality
    attn_kernel<<<dim3(16, 8, 8), 256, 0, stream>>>(qb, kb, vbT, ob);

    // t2.5: w_proj -> wprojT (into dead qb region)
    wprep<<<dim3(1024 / 64, 1024 / 64), 256, 0, stream>>>(
        (const float*)w_proj, wprojT, 1024, 1024);

    // t3: proj GEMM -> fp32 out (R7 kernel; reads only ws)
    gemm_bt<0, float><<<dim3(1024 / 128, 8192 / 128), 256, 0, stream>>>(
        ob, wprojT, (const float*)b_proj, out, nullptr, nullptr, nullptr,
        8192, 1024, 1024);
}

// Round 3
// 255.530 us; speedup vs baseline: 1.0336x; 1.0336x over previous
//
#include <hip/hip_runtime.h>
#include <hip/hip_bf16.h>
#include <cstdint>

// B=8, N=1024, D=1024, H=16, hd=64, scale=1/8.
// Facts: inputs fp32, output fp32, ws = 64 MiB, threshold 1.47e-3 (bf16
// intermediates give 4.9e-4 — R6/R7 verified). R7 swizzled-LDS GEMM verified
// on HW (0 bank conflicts, correct). R8: A pre-converted to bf16 (d_out as
// scratch), softmax without max-subtraction (shift-invariant; scores |s|<~3).
// R9: attention on 32x32x16 MFMA, swapped QK^T, in-register P redistribution
// (cvt_pk_bf16 + permlane32_swap), no Ps LDS. Verified (absmax 4.9e-4).
// R10 POST-MORTEM: 8-phase 256^2 port REGRESSED (106 vs 90 us; MfmaUtil 19.6,
// VALUBusy 14 — latency-serialized). Causes: per-phase sched_barrier(0)
// order-pinning (m141 class), schedule != m201 geometry (m232 precedent:
// naive 8-phase ports land below 2-phase), 384 blocks @ 1/CU = 1.5 rounds.
// R11: revert QKV to R7 gemm_bt (proven 90 us); fuse aprep+wprep(qkv) into
// one launch (launch-gap ~60 us total is material); T5 setprio around attn
// MFMA clusters (4-5 independent blocks/CU at different kt phases = the
// m191 attn regime where setprio pays +4-7%; NOT the m190 lockstep null).

typedef __attribute__((ext_vector_type(8))) short short8;   // 8 bf16
typedef __attribute__((ext_vector_type(4))) float floatx4;  // 16x16 MFMA acc
typedef __attribute__((ext_vector_type(16))) float f32x16;  // 32x32 MFMA acc
typedef __attribute__((ext_vector_type(2))) unsigned int uint2v;

__device__ __forceinline__ ushort f2bf(float f) {
    union { float f; uint32_t i; } v; v.f = f;
    uint32_t r = v.i + 0x7fffu + ((v.i >> 16) & 1u);  // RNE
    return (ushort)(r >> 16);
}
__device__ __forceinline__ uint32_t pack2(float a, float b) {
    return (uint32_t)f2bf(a) | ((uint32_t)f2bf(b) << 16);
}
__device__ __forceinline__ uint32_t cvtpk_bf16(float a, float b) {
    uint32_t r;
    asm("v_cvt_pk_bf16_f32 %0, %1, %2" : "=v"(r) : "v"(a), "v"(b));
    return r;  // low16 = bf16(a), high16 = bf16(b)
}
__device__ __forceinline__ void gl2lds16(const void* g, void* lds) {
    __builtin_amdgcn_global_load_lds(
        (const __attribute__((address_space(1))) uint32_t*)(uintptr_t)g,
        (__attribute__((address_space(3))) uint32_t*)(uintptr_t)lds,
        16, 0, 0);
}

// ---------------------------------------------------------------------------
// Fused prep: blocks [0, nA) do A fp32->bf16 (8 floats/thread);
// blocks [nA, nA+768) transpose w_qkv fp32 [1024,3072] -> wqkvT bf16
// [3072,1024]. One launch instead of two (launch-gap reduction).
// ---------------------------------------------------------------------------
__global__ __launch_bounds__(256)
void prep_fused(const float* __restrict__ in, ushort* __restrict__ ob,
                const float* __restrict__ W, ushort* __restrict__ WT,
                int nA) {
    __shared__ ushort T[64 * 72];
    const int tid = threadIdx.x;
    int bx = blockIdx.x;
    if (bx < nA) {
        const int i = (bx * 256 + tid) * 8;
        const float4 f0 = *(const float4*)&in[i];
        const float4 f1 = *(const float4*)&in[i + 4];
        uint4 pk;
        pk.x = pack2(f0.x, f0.y); pk.y = pack2(f0.z, f0.w);
        pk.z = pack2(f1.x, f1.y); pk.w = pack2(f1.z, f1.w);
        *(uint4*)&ob[i] = pk;
        return;
    }
    bx -= nA;                      // 768 blocks -> (x=48, y=16)
    const int K = 1024, N = 3072;
    const int k0 = (bx / 48) * 64, n0 = (bx % 48) * 64;
#pragma unroll
    for (int i = 0; i < 4; ++i) {
        int c = tid + i * 256;
        int kl = c >> 4, n4 = (c & 15) << 2;
        const float4 f = *(const float4*)&W[(size_t)(k0 + kl) * N + n0 + n4];
        T[(n4 + 0) * 72 + kl] = f2bf(f.x);
        T[(n4 + 1) * 72 + kl] = f2bf(f.y);
        T[(n4 + 2) * 72 + kl] = f2bf(f.z);
        T[(n4 + 3) * 72 + kl] = f2bf(f.w);
    }
    __syncthreads();
#pragma unroll
    for (int i = 0; i < 2; ++i) {
        int c = tid + i * 256;
        int nl = c >> 3, k8 = (c & 7) << 3;
        *(uint4*)&WT[(size_t)(n0 + nl) * K + k0 + k8] =
            *(const uint4*)&T[nl * 72 + k8];
    }
}

// ---------------------------------------------------------------------------
// Weight prep: W fp32 [K,N] -> WT bf16 [N,K]. (proj weights; must run after
// attn because wprojT lives in the qb region.)
// ---------------------------------------------------------------------------
__global__ __launch_bounds__(256)
void wprep(const float* __restrict__ W, ushort* __restrict__ WT,
           int K, int N) {
    __shared__ ushort T[64 * 72];
    const int tid = threadIdx.x;
    const int k0 = blockIdx.y * 64, n0 = blockIdx.x * 64;
#pragma unroll
    for (int i = 0; i < 4; ++i) {
        int c = tid + i * 256;
        int kl = c >> 4, n4 = (c & 15) << 2;
        const float4 f = *(const float4*)&W[(size_t)(k0 + kl) * N + n0 + n4];
        T[(n4 + 0) * 72 + kl] = f2bf(f.x);
        T[(n4 + 1) * 72 + kl] = f2bf(f.y);
        T[(n4 + 2) * 72 + kl] = f2bf(f.z);
        T[(n4 + 3) * 72 + kl] = f2bf(f.w);
    }
    __syncthreads();
#pragma unroll
    for (int i = 0; i < 2; ++i) {
        int c = tid + i * 256;
        int nl = c >> 3, k8 = (c & 7) << 3;
        *(uint4*)&WT[(size_t)(n0 + nl) * K + k0 + k8] =
            *(const uint4*)&T[nl * 72 + k8];
    }
}

// ---------------------------------------------------------------------------
// BT-GEMM (all-bf16): C[M,N] = A[M,K]*BT[N,K]^T + bias[N]. BM=BN=128, BK=64.
// Swizzled unpadded LDS (R7 HW-verified: 0 conflicts). Dual global_load_lds.
// MODE 0: row-major OutT store. MODE 1: QKV scatter (V transposed).
// ---------------------------------------------------------------------------
template <int MODE, typename OutT>
__global__ __launch_bounds__(256)
void gemm_bt(const ushort* __restrict__ A, const ushort* __restrict__ BT,
             const float* __restrict__ bias, OutT* __restrict__ C,
             ushort* __restrict__ qb, ushort* __restrict__ kb,
             ushort* __restrict__ vb, int M, int Nn, int K) {
    __shared__ ushort As[128 * 64];
    __shared__ ushort Bs[128 * 64];
    const int tid = threadIdx.x;
    const int lane = tid & 63, w = tid >> 6;
    const int wm = w & 1, wn = w >> 1;
    const int l16 = lane & 15, quad = lane >> 4;
    const int m0 = blockIdx.y * 128, n0 = blockIdx.x * 128;
    const int srow = lane >> 3;
    const int cg = (lane & 7) ^ srow;
    const int sx = l16 & 7;

    floatx4 acc[4][4];
#pragma unroll
    for (int i = 0; i < 4; ++i)
#pragma unroll
        for (int j = 0; j < 4; ++j) acc[i][j] = (floatx4)0.f;

    const int nkt = K >> 6;
    for (int kt = 0; kt < nkt; ++kt) {
        __syncthreads();
#pragma unroll
        for (int i = 0; i < 4; ++i) {
            const int row = w * 32 + i * 8 + srow;
            gl2lds16(&BT[(size_t)(n0 + row) * K + kt * 64 + cg * 8],
                     &Bs[(w * 32 + i * 8) * 64]);
            gl2lds16(&A[(size_t)(m0 + row) * K + kt * 64 + cg * 8],
                     &As[(w * 32 + i * 8) * 64]);
        }
        __syncthreads();
#pragma unroll
        for (int kk = 0; kk < 2; ++kk) {
            const int sl = ((kk << 2) | quad) ^ sx;
            short8 af[4], bfr[4];
#pragma unroll
            for (int mi = 0; mi < 4; ++mi)
                af[mi] = *(const short8*)&As[(wm * 64 + mi * 16 + l16) * 64 +
                                             sl * 8];
#pragma unroll
            for (int ni = 0; ni < 4; ++ni)
                bfr[ni] = *(const short8*)&Bs[(wn * 64 + ni * 16 + l16) * 64 +
                                              sl * 8];
#pragma unroll
            for (int mi = 0; mi < 4; ++mi)
#pragma unroll
                for (int ni = 0; ni < 4; ++ni)
                    acc[mi][ni] = __builtin_amdgcn_mfma_f32_16x16x32_bf16(
                        af[mi], bfr[ni], acc[mi][ni], 0, 0, 0);
        }
    }

#pragma unroll
    for (int mi = 0; mi < 4; ++mi) {
#pragma unroll
        for (int ni = 0; ni < 4; ++ni) {
            const int jg = n0 + wn * 64 + ni * 16 + l16;
            const float bv = bias[jg];
#pragma unroll
            for (int r = 0; r < 4; ++r) {
                const int mg = m0 + wm * 64 + mi * 16 + quad * 4 + r;
                const float vout = acc[mi][ni][r] + bv;
                if (MODE == 0) {
                    if (sizeof(OutT) == 4)
                        ((float*)C)[(size_t)mg * Nn + jg] = vout;
                    else
                        ((ushort*)C)[(size_t)mg * Nn + jg] = f2bf(vout);
                } else {
                    const int which = jg >> 10;
                    const int h = (jg & 1023) >> 6;
                    const int d = jg & 63;
                    const int bb = mg >> 10, nn = mg & 1023;
                    if (which == 0)
                        qb[(size_t)((bb * 16 + h) * 1024 + nn) * 64 + d] =
                            f2bf(vout);
                    else if (which == 1)
                        kb[(size_t)((bb * 16 + h) * 1024 + nn) * 64 + d] =
                            f2bf(vout);
                    else  // V pre-transposed: [B,H,hd,N]
                        vb[((size_t)(bb * 16 + h) * 64 + d) * 1024 + nn] =
                            f2bf(vout);
                }
            }
        }
    }
}

// ---------------------------------------------------------------------------
// Flash attention (R9): 32x32x16 MFMA, swapped QK^T, in-register P.
// R11: + T5 setprio(1) around the MFMA clusters (independent blocks/CU at
// different kt phases -> scheduler has something to arbitrate, m191 regime).
// ---------------------------------------------------------------------------
__global__ __launch_bounds__(256, 4)
void attn_kernel(const ushort* __restrict__ q, const ushort* __restrict__ k,
                 const ushort* __restrict__ v, ushort* __restrict__ o) {
    __shared__ ushort Qs[128 * 64];
    __shared__ ushort Ks[64 * 64];
    __shared__ ushort VTs[64 * 64];      // VT[d][key]
    const int tid = threadIdx.x;
    const int lane = tid & 63, w = tid >> 6;
    const int l31 = lane & 31, hi = lane >> 5, l7 = lane & 7;
    const int h = blockIdx.x, qt = blockIdx.y, b = blockIdx.z;
    // linear id = h + 16*qt + 128*b -> all 8 q-tiles of a head land on the
    // same XCD (id mod 8 == h&7); per-XCD K/V working set = 16 heads * 256KB
    // = 4 MB = one L2.
    const size_t head_off = (size_t)(b * 16 + h) * 1024 * 64;
    const ushort* Qp = q + head_off + (size_t)qt * 128 * 64;
    const ushort* Vp = v + head_off;     // [64 d][1024 key]
    const int srow = lane >> 3;
    const int cg = (lane & 7) ^ srow;
    const float CEXP = 0.125f * 1.44269504f;  // scale * log2(e)

#pragma unroll
    for (int g = 0; g < 4; ++g)
        gl2lds16(&Qp[(size_t)(w * 32 + g * 8 + srow) * 64 + cg * 8],
                 &Qs[(w * 32 + g * 8) * 64]);
    __syncthreads();

    // Q fragment (B-operand of swapped QK^T): col=q=lane&31, k=hd c*16+hi*8+j
    short8 bq[4];
#pragma unroll
    for (int c = 0; c < 4; ++c)
        bq[c] = *(const short8*)&Qs[(w * 32 + l31) * 64 +
                                    ((2 * c + hi) ^ l7) * 8];

    f32x16 oacc[2];
    oacc[0] = (f32x16)0.f;
    oacc[1] = (f32x16)0.f;
    float ls = 0.f;

    for (int kt = 0; kt < 16; ++kt) {
        __syncthreads();
        const ushort* Kp = k + head_off + (size_t)kt * 64 * 64;
#pragma unroll
        for (int g = 0; g < 2; ++g) {
            gl2lds16(&Kp[(size_t)(w * 16 + g * 8 + srow) * 64 + cg * 8],
                     &Ks[(w * 16 + g * 8) * 64]);
            gl2lds16(&Vp[(size_t)(w * 16 + g * 8 + srow) * 1024 +
                         kt * 64 + cg * 8],
                     &VTs[(w * 16 + g * 8) * 64]);
        }
        __syncthreads();

#pragma unroll
        for (int st = 0; st < 2; ++st) {
            // S^T = K_st * Q^T : A=K rows (key), B=Q rows (q)
            f32x16 sacc = (f32x16)0.f;
            __builtin_amdgcn_s_setprio(1);
#pragma unroll
            for (int c = 0; c < 4; ++c) {
                short8 ak = *(const short8*)&Ks[(st * 32 + l31) * 64 +
                                                ((2 * c + hi) ^ l7) * 8];
                sacc = __builtin_amdgcn_mfma_f32_32x32x16_bf16(
                    ak, bq[c], sacc, 0, 0, 0);
            }
            __builtin_amdgcn_s_setprio(0);
            // sacc[r] = S[key = st*32 + (r&3)+8*(r>>2)+4*hi][q = w*32+l31]
            uint32_t wd[8];
#pragma unroll
            for (int i = 0; i < 8; ++i) {
                const float e0 = __builtin_amdgcn_exp2f(sacc[2 * i] * CEXP);
                const float e1 = __builtin_amdgcn_exp2f(sacc[2 * i + 1] * CEXP);
                ls += e0 + e1;
                wd[i] = cvtpk_bf16(e0, e1);  // keys {base, base+1}
            }
            // wd[i] keys: 8*(i>>1) + 2*(i&1) + 4*hi + {0,1}.
            // permlane32_swap: ret[0]={vdst.lo,vsrc.lo}, ret[1]={vdst.hi,vsrc.hi}
            short8 ap[2];
#pragma unroll
            for (int c2 = 0; c2 < 2; ++c2) {
                uint2v sA = __builtin_amdgcn_permlane32_swap(
                    wd[4 * c2 + 0], wd[4 * c2 + 2], false, false);
                uint2v sB = __builtin_amdgcn_permlane32_swap(
                    wd[4 * c2 + 1], wd[4 * c2 + 3], false, false);
                union { uint32_t u[4]; short8 s; } t;
                t.u[0] = sA[0]; t.u[1] = sB[0];
                t.u[2] = sA[1]; t.u[3] = sB[1];
                ap[c2] = t.s;  // A[row=q=l31][k = c2*16 + hi*8 + j]
            }
            // O += P V : B = VT rows (d), k = key
            __builtin_amdgcn_s_setprio(1);
#pragma unroll
            for (int dt = 0; dt < 2; ++dt)
#pragma unroll
                for (int c2 = 0; c2 < 2; ++c2) {
                    short8 bv = *(const short8*)&VTs[
                        (dt * 32 + l31) * 64 +
                        ((st * 4 + c2 * 2 + hi) ^ l7) * 8];
                    oacc[dt] = __builtin_amdgcn_mfma_f32_32x32x16_bf16(
                        ap[c2], bv, oacc[dt], 0, 0, 0);
                }
            __builtin_amdgcn_s_setprio(0);
        }
    }

    // merge hi-half partial sums: each lane then holds full sum for q=l31
    ls += __shfl_xor(ls, 32, 64);
    const float inv = 1.f / ls;

    // oacc[dt][r]: O[q = w*32 + (r&3)+8*(r>>2)+4*hi][d = dt*32 + l31]
#pragma unroll
    for (int r = 0; r < 16; ++r) {
        const int qout = (r & 3) + ((r >> 2) << 3) + (hi << 2);
        const float iq = __shfl(inv, qout, 64);
        const int n = qt * 128 + w * 32 + qout;
#pragma unroll
        for (int dt = 0; dt < 2; ++dt)
            o[((size_t)(b * 1024 + n)) * 1024 + h * 64 + dt * 32 + l31] =
                f2bf(oacc[dt][r] * iq);
    }
}

// ---------------------------------------------------------------------------
extern "C" void kernel_launch(void* const* d_in, const int* in_sizes, int n_in,
                              void* d_out, int out_size, void* d_ws,
                              size_t ws_size, hipStream_t stream) {
    const void *inp = d_in[0], *w_qkv = d_in[1], *b_qkv = d_in[2],
               *w_proj = d_in[3], *b_proj = d_in[4];
    for (int i = 0; i < n_in; ++i) {
        switch (in_sizes[i]) {
            case 8 * 1024 * 1024: inp    = d_in[i]; break;
            case 3 * 1024 * 1024: w_qkv  = d_in[i]; break;
            case 3072:            b_qkv  = d_in[i]; break;
            case 1024 * 1024:     w_proj = d_in[i]; break;
            case 1024:            b_proj = d_in[i]; break;
        }
    }
    float* out = (float*)d_out;

    // ws (64 MiB): [0,16M) qb -> later wprojT; [16,32M) kb; [32,48M) vbT;
    // [48,64M) ob, whose first 6.3 MB first hosts wqkvT (dead before attn).
    // d_out (32 MB fp32): first 16.8 MB used as bf16-A scratch until the
    // final proj GEMM overwrites all of d_out (proj reads only ws).
    char* ws = (char*)d_ws;
    ushort* qb  = (ushort*)(ws);
    ushort* kb  = (ushort*)(ws + (size_t)16 * 1024 * 1024);
    ushort* vbT = (ushort*)(ws + (size_t)32 * 1024 * 1024);
    ushort* ob  = (ushort*)(ws + (size_t)48 * 1024 * 1024);
    ushort* wqkvT  = ob;
    ushort* wprojT = qb;
    ushort* abf = (ushort*)d_out;   // 16.8 MB bf16 scratch inside d_out

    // t0: fused prep — inp fp32 -> bf16 (4096 blocks) + w_qkv -> wqkvT
    // (768 blocks) in one launch
    prep_fused<<<4096 + 768, 256, 0, stream>>>(
        (const float*)inp, abf, (const float*)w_qkv, wqkvT, 4096);

    // t1: QKV GEMM (R7 2-phase 128x128) -> scatter q/k/vT
    gemm_bt<1, ushort><<<dim3(3072 / 128, 8192 / 128), 256, 0, stream>>>(
        abf, wqkvT, (const float*)b_qkv, (ushort*)nullptr, qb, kb, vbT,
        8192, 3072, 1024);

    // t2: attention — grid (h, qt, b): head-major for XCD/L2 locality
    attn_kernel<<<dim3(16, 8, 8), 256, 0, stream>>>(qb, kb, vbT, ob);

    // t2.5: w_proj -> wprojT (into dead qb region)
    wprep<<<dim3(1024 / 64, 1024 / 64), 256, 0, stream>>>(
        (const float*)w_proj, wprojT, 1024, 1024);

    // t3: proj GEMM -> fp32 out (R7 kernel; reads only ws)
    gemm_bt<0, float><<<dim3(1024 / 128, 8192 / 128), 256, 0, stream>>>(
        ob, wprojT, (const float*)b_proj, out, nullptr, nullptr, nullptr,
        8192, 1024, 1024);
}